// Round 1
// baseline (2026.715 us; speedup 1.0000x reference)
//
#include <hip/hip_runtime.h>
#include <hip/hip_bf16.h>
#include <math.h>

#define BB 8
#define CC 128
#define HH 48
#define WW2 48
#define NTOK 2304   // H*W
#define KTOP 1843   // int(2304*0.8)

// ---------------- Kernel 1: QKV projections ----------------
// t[b] = x[b] viewed as [N, C] (raw reshape). Q = t@Wq.T+bq etc.
// Q,V stored [B,N,C]; K stored transposed [B,C,N] for coalesced QK^T.
__global__ __launch_bounds__(256) void qkv_kernel(
    const float* __restrict__ x,
    const float* __restrict__ Wq, const float* __restrict__ bq,
    const float* __restrict__ Wk, const float* __restrict__ bk,
    const float* __restrict__ Wv, const float* __restrict__ bv,
    float* __restrict__ q_ws, float* __restrict__ kt_ws, float* __restrict__ v_ws)
{
    __shared__ float t_lds[128 * 68];   // [c][r], padded to 68 for banks+alignment
    int blk = blockIdx.x;
    int b  = blk / 36;
    int n0 = (blk % 36) * 64;
    int tid = threadIdx.x;
    const float* xb = x + (size_t)(b * NTOK + n0) * CC;
    #pragma unroll
    for (int k = 0; k < 32; ++k) {
        int idx = k * 256 + tid;
        int r = idx >> 7, c = idx & 127;
        t_lds[c * 68 + r] = xb[idx];
    }
    __syncthreads();
    int o  = tid & 127;
    int rh = tid >> 7;                 // row half: rows rh*32 .. rh*32+31
    const float* Ws[3] = {Wq, Wk, Wv};
    const float* bs[3] = {bq, bk, bv};
    for (int mat = 0; mat < 3; ++mat) {
        const float* W = Ws[mat];
        float acc[32];
        #pragma unroll
        for (int j = 0; j < 32; ++j) acc[j] = 0.f;
        for (int c = 0; c < 128; ++c) {
            float w = W[o * 128 + c];
            const float4* t4p = (const float4*)&t_lds[c * 68 + rh * 32];
            #pragma unroll
            for (int j4 = 0; j4 < 8; ++j4) {
                float4 t4 = t4p[j4];
                acc[j4*4+0] += t4.x * w;
                acc[j4*4+1] += t4.y * w;
                acc[j4*4+2] += t4.z * w;
                acc[j4*4+3] += t4.w * w;
            }
        }
        float bias = bs[mat][o];
        if (mat == 1) {
            float* kp = kt_ws + (size_t)(b * CC + o) * NTOK + n0 + rh * 32;
            #pragma unroll
            for (int j = 0; j < 32; ++j) kp[j] = acc[j] + bias;
        } else {
            float* op = (mat == 0 ? q_ws : v_ws)
                        + (size_t)(b * NTOK + n0 + rh * 32) * CC + o;
            #pragma unroll
            for (int j = 0; j < 32; ++j) op[(size_t)j * CC] = acc[j] + bias;
        }
    }
}

// ---------------- Kernel 2: fused attention (4 rows per block) ----------------
// Per row: s = Q_row @ K^T / sqrt(C); exact top-KTOP threshold via 32-bit
// binary search on monotone-mapped keys; softmax over kept; out = p @ V.
__global__ __launch_bounds__(256) void attn_kernel(
    const float* __restrict__ q_ws, const float* __restrict__ kt_ws,
    const float* __restrict__ v_ws, float* __restrict__ xs_ws)
{
    __shared__ float qi[4 * 128];        // [c][r] interleaved
    __shared__ float s_int[NTOK * 4];    // [m][r] interleaved
    __shared__ float outp[2 * 4 * 128];  // [half][r][c]
    __shared__ float rowinv[4];
    int tid = threadIdx.x;
    int blk = blockIdx.x;
    int b  = blk / 576;
    int n0 = (blk % 576) * 4;

    // Phase A: load 4 Q rows, interleaved
    for (int k = tid; k < 512; k += 256) {
        int r = k >> 7, c = k & 127;
        qi[c * 4 + r] = q_ws[(size_t)(b * NTOK + n0 + r) * CC + c];
    }
    __syncthreads();

    // Phase B: S = Q K^T * scale. Thread handles 4 consecutive m.
    const float scale = 0.08838834764831845f;  // 1/sqrt(128)
    const float* ktb = kt_ws + (size_t)b * CC * NTOK;
    for (int m0 = 0; m0 < NTOK; m0 += 1024) {
        int m = m0 + tid * 4;
        if (m < NTOK) {
            float acc[4][4];
            #pragma unroll
            for (int mm = 0; mm < 4; ++mm)
                #pragma unroll
                for (int r = 0; r < 4; ++r) acc[mm][r] = 0.f;
            for (int c = 0; c < 128; ++c) {
                float4 q4 = *(const float4*)&qi[c * 4];
                float4 k4 = *(const float4*)&ktb[(size_t)c * NTOK + m];
                acc[0][0] += k4.x * q4.x; acc[0][1] += k4.x * q4.y;
                acc[0][2] += k4.x * q4.z; acc[0][3] += k4.x * q4.w;
                acc[1][0] += k4.y * q4.x; acc[1][1] += k4.y * q4.y;
                acc[1][2] += k4.y * q4.z; acc[1][3] += k4.y * q4.w;
                acc[2][0] += k4.z * q4.x; acc[2][1] += k4.z * q4.y;
                acc[2][2] += k4.z * q4.z; acc[2][3] += k4.z * q4.w;
                acc[3][0] += k4.w * q4.x; acc[3][1] += k4.w * q4.y;
                acc[3][2] += k4.w * q4.z; acc[3][3] += k4.w * q4.w;
            }
            #pragma unroll
            for (int mm = 0; mm < 4; ++mm) {
                float4 st;
                st.x = acc[mm][0] * scale; st.y = acc[mm][1] * scale;
                st.z = acc[mm][2] * scale; st.w = acc[mm][3] * scale;
                *(float4*)&s_int[(m + mm) * 4] = st;
            }
        }
    }
    __syncthreads();

    // Phase C+D: per-wave exact top-k threshold + softmax (wave wid owns row wid)
    int wid = tid >> 6;
    int lane = tid & 63;
    unsigned int keys[36];
    float vmax = -1e30f;
    #pragma unroll
    for (int j = 0; j < 36; ++j) {
        int m = lane + j * 64;
        float v = s_int[m * 4 + wid];
        unsigned int u = __float_as_uint(v);
        u = (u & 0x80000000u) ? ~u : (u | 0x80000000u);
        keys[j] = u;
        vmax = fmaxf(vmax, v);
    }
    #pragma unroll
    for (int off = 32; off; off >>= 1) vmax = fmaxf(vmax, __shfl_xor(vmax, off, 64));
    unsigned int res = 0;
    for (int bit = 31; bit >= 0; --bit) {
        unsigned int cand = res | (1u << bit);
        int cnt = 0;
        #pragma unroll
        for (int j = 0; j < 36; ++j) cnt += (keys[j] >= cand) ? 1 : 0;
        #pragma unroll
        for (int off = 32; off; off >>= 1) cnt += __shfl_xor(cnt, off, 64);
        if (cnt >= KTOP) res = cand;
    }
    float lsum = 0.f;
    #pragma unroll
    for (int j = 0; j < 36; ++j) {
        int m = lane + j * 64;
        float e = 0.f;
        if (keys[j] >= res) e = __expf(s_int[m * 4 + wid] - vmax);
        s_int[m * 4 + wid] = e;
        lsum += e;
    }
    #pragma unroll
    for (int off = 32; off; off >>= 1) lsum += __shfl_xor(lsum, off, 64);
    if (lane == 0) rowinv[wid] = 1.f / lsum;
    __syncthreads();

    // Phase E: out[r][c] = sum_m p[r][m] * V[m][c]
    int c = tid & 127;
    int half = tid >> 7;
    float acc[4] = {0.f, 0.f, 0.f, 0.f};
    const float* vb = v_ws + (size_t)b * NTOK * CC + c;
    int mstart = half * 1152;
    for (int m = mstart; m < mstart + 1152; ++m) {
        float v = vb[(size_t)m * CC];
        float4 s4 = *(const float4*)&s_int[m * 4];
        acc[0] += s4.x * v; acc[1] += s4.y * v;
        acc[2] += s4.z * v; acc[3] += s4.w * v;
    }
    #pragma unroll
    for (int r = 0; r < 4; ++r) outp[(half * 4 + r) * 128 + c] = acc[r];
    __syncthreads();
    for (int k = tid; k < 512; k += 256) {
        int r = k >> 7;
        int c2 = k & 127;
        float v = (outp[r * 128 + c2] + outp[(4 + r) * 128 + c2]) * rowinv[r];
        xs_ws[(size_t)(b * NTOK + n0 + r) * CC + c2] = v;
    }
}

// ---------------- Kernel 3: gate conv + sigmoid -> importance [B,HW] ----------
__global__ __launch_bounds__(256) void gate_kernel(
    const float* __restrict__ xs_ws, const float* __restrict__ gw,
    const float* __restrict__ gb, float* __restrict__ imp_ws)
{
    int b = blockIdx.x / 9;
    int p = (blockIdx.x % 9) * 256 + threadIdx.x;
    int h = p / 48, w = p % 48;
    float acc = gb[0];
    const float* xb = xs_ws + (size_t)b * CC * NTOK;
    for (int i = 0; i < 128; ++i) {
        const float* plane = xb + (size_t)i * NTOK;
        const float* wv = gw + i * 9;
        #pragma unroll
        for (int kh = 0; kh < 3; ++kh) {
            int hh = h + kh - 1;
            if ((unsigned)hh >= 48u) continue;
            #pragma unroll
            for (int kw = 0; kw < 3; ++kw) {
                int ww = w + kw - 1;
                if ((unsigned)ww >= 48u) continue;
                acc += plane[hh * 48 + ww] * wv[kh * 3 + kw];
            }
        }
    }
    imp_ws[b * NTOK + p] = 1.f / (1.f + __expf(-acc));
}

// ---------------- Kernel 4: ref conv on gated xs + residual + temporal -------
__global__ __launch_bounds__(256) void refconv_kernel(
    const float* __restrict__ xs_ws, const float* __restrict__ imp_ws,
    const float* __restrict__ rw, const float* __restrict__ rb,
    const float* __restrict__ prev, float* __restrict__ xs2_ws)
{
    __shared__ float plane[50 * 50];
    int b = blockIdx.x >> 7;
    int o = blockIdx.x & 127;
    int tid = threadIdx.x;
    float acc[9];
    #pragma unroll
    for (int q = 0; q < 9; ++q) acc[q] = 0.f;
    const float* xb = xs_ws + (size_t)b * CC * NTOK;
    const float* ib = imp_ws + b * NTOK;
    for (int i = 0; i < 128; ++i) {
        __syncthreads();
        for (int idx = tid; idx < 2500; idx += 256) {
            int r = idx / 50, c = idx % 50;
            int h = r - 1, w = c - 1;
            float v = 0.f;
            if ((unsigned)h < 48u && (unsigned)w < 48u) {
                int pp = h * 48 + w;
                v = xb[(size_t)i * NTOK + pp] * ib[pp];
            }
            plane[idx] = v;
        }
        __syncthreads();
        float wv[9];
        const float* wp = rw + ((size_t)o * 128 + i) * 9;
        #pragma unroll
        for (int k = 0; k < 9; ++k) wv[k] = wp[k];
        #pragma unroll
        for (int q = 0; q < 9; ++q) {
            int p = q * 256 + tid;
            int h = p / 48, w = p % 48;
            float s = 0.f;
            #pragma unroll
            for (int kh = 0; kh < 3; ++kh)
                #pragma unroll
                for (int kw = 0; kw < 3; ++kw)
                    s += plane[(h + kh) * 50 + (w + kw)] * wv[kh * 3 + kw];
            acc[q] += s;
        }
    }
    float bias = rb[o];
    const float* xso = xs_ws + ((size_t)b * CC + o) * NTOK;
    const float* pv  = prev  + ((size_t)b * CC + o) * NTOK;
    float* op = xs2_ws + ((size_t)b * CC + o) * NTOK;
    #pragma unroll
    for (int q = 0; q < 9; ++q) {
        int p = q * 256 + tid;
        op[p] = acc[q] + bias + xso[p] + 0.5f * pv[p];
    }
}

// ---------------- Kernel 5: coverage conv (3x3, dilation 2, pad 2) -----------
__global__ __launch_bounds__(256) void covconv_kernel(
    const float* __restrict__ xs2_ws, const float* __restrict__ cw,
    const float* __restrict__ cb, float* __restrict__ out)
{
    __shared__ float plane[52 * 52];
    int b = blockIdx.x >> 7;
    int o = blockIdx.x & 127;
    int tid = threadIdx.x;
    float acc[9];
    #pragma unroll
    for (int q = 0; q < 9; ++q) acc[q] = 0.f;
    const float* xb = xs2_ws + (size_t)b * CC * NTOK;
    for (int i = 0; i < 128; ++i) {
        __syncthreads();
        for (int idx = tid; idx < 2704; idx += 256) {
            int r = idx / 52, c = idx % 52;
            int h = r - 2, w = c - 2;
            float v = 0.f;
            if ((unsigned)h < 48u && (unsigned)w < 48u) v = xb[(size_t)i * NTOK + h * 48 + w];
            plane[idx] = v;
        }
        __syncthreads();
        float wv[9];
        const float* wp = cw + ((size_t)o * 128 + i) * 9;
        #pragma unroll
        for (int k = 0; k < 9; ++k) wv[k] = wp[k];
        #pragma unroll
        for (int q = 0; q < 9; ++q) {
            int p = q * 256 + tid;
            int h = p / 48, w = p % 48;
            float s = 0.f;
            #pragma unroll
            for (int kh = 0; kh < 3; ++kh)
                #pragma unroll
                for (int kw = 0; kw < 3; ++kw)
                    s += plane[(h + 2 * kh) * 52 + (w + 2 * kw)] * wv[kh * 3 + kw];
            acc[q] += s;
        }
    }
    float bias = cb[o];
    float* op = out + ((size_t)b * CC + o) * NTOK;
    #pragma unroll
    for (int q = 0; q < 9; ++q) op[q * 256 + tid] = acc[q] + bias;
}

extern "C" void kernel_launch(void* const* d_in, const int* in_sizes, int n_in,
                              void* d_out, int out_size, void* d_ws, size_t ws_size,
                              hipStream_t stream)
{
    const float* x    = (const float*)d_in[0];
    const float* prev = (const float*)d_in[1];
    const float* Wq   = (const float*)d_in[2];
    const float* bq   = (const float*)d_in[3];
    const float* Wk   = (const float*)d_in[4];
    const float* bk   = (const float*)d_in[5];
    const float* Wv   = (const float*)d_in[6];
    const float* bv   = (const float*)d_in[7];
    const float* rw   = (const float*)d_in[8];
    const float* rb   = (const float*)d_in[9];
    const float* gw   = (const float*)d_in[10];
    const float* gb   = (const float*)d_in[11];
    const float* cw   = (const float*)d_in[12];
    const float* cb   = (const float*)d_in[13];
    float* out = (float*)d_out;
    float* ws  = (float*)d_ws;

    const size_t SZ = (size_t)BB * NTOK * CC;  // 2359296 floats
    float* q_ws   = ws;
    float* kt_ws  = ws + SZ;
    float* v_ws   = ws + 2 * SZ;
    float* xs_ws  = ws + 3 * SZ;
    float* imp_ws = ws + 4 * SZ;
    float* xs2_ws = ws + 4 * SZ + (size_t)BB * NTOK;
    // total ws use: 5*SZ + B*NTOK floats ≈ 47.3 MB

    qkv_kernel<<<dim3(288), dim3(256), 0, stream>>>(x, Wq, bq, Wk, bk, Wv, bv,
                                                    q_ws, kt_ws, v_ws);
    attn_kernel<<<dim3(4608), dim3(256), 0, stream>>>(q_ws, kt_ws, v_ws, xs_ws);
    gate_kernel<<<dim3(72), dim3(256), 0, stream>>>(xs_ws, gw, gb, imp_ws);
    refconv_kernel<<<dim3(1024), dim3(256), 0, stream>>>(xs_ws, imp_ws, rw, rb,
                                                         prev, xs2_ws);
    covconv_kernel<<<dim3(1024), dim3(256), 0, stream>>>(xs2_ws, cw, cb, out);
}

// Round 2
// 1685.218 us; speedup vs baseline: 1.2026x; 1.2026x over previous
//
#include <hip/hip_runtime.h>
#include <hip/hip_bf16.h>
#include <math.h>

#define BB 8
#define CC 128
#define NTOK 2304   // 48*48
#define KTOP 1843   // int(2304*0.8)

typedef unsigned short u16;
typedef unsigned int   u32;

static __device__ __forceinline__ float bf2f(u16 u) {
    return __uint_as_float(((u32)u) << 16);
}
static __device__ __forceinline__ u16 f2bf(float f) {
    u32 x = __float_as_uint(f);
    return (u16)((x + 0x7fffu + ((x >> 16) & 1u)) >> 16);  // RNE
}

// ---------------- Kernel 1: QKV projections (bf16 outputs) ----------------
// Q,V: [B,N,C] bf16 (coalesced via LDS transpose staging); K^T: [B,C,N] bf16.
__global__ __launch_bounds__(256) void qkv_kernel(
    const float* __restrict__ x,
    const float* __restrict__ Wq, const float* __restrict__ bq,
    const float* __restrict__ Wk, const float* __restrict__ bk,
    const float* __restrict__ Wv, const float* __restrict__ bv,
    u16* __restrict__ q_ws, u16* __restrict__ kt_ws, u16* __restrict__ v_ws)
{
    __shared__ float t_lds[128 * 68];   // [c][r]
    __shared__ u16 st[64 * 128];        // transpose staging for q/v stores
    int blk = blockIdx.x;
    int b  = blk / 36;
    int n0 = (blk % 36) * 64;
    int tid = threadIdx.x;
    const float* xb = x + (size_t)(b * NTOK + n0) * CC;
    #pragma unroll
    for (int k = 0; k < 32; ++k) {
        int idx = k * 256 + tid;
        t_lds[(idx & 127) * 68 + (idx >> 7)] = xb[idx];
    }
    __syncthreads();
    int o  = tid & 127;
    int rh = tid >> 7;
    const float* Ws[3] = {Wq, Wk, Wv};
    const float* bs[3] = {bq, bk, bv};
    for (int mat = 0; mat < 3; ++mat) {
        const float* W = Ws[mat];
        float acc[32];
        #pragma unroll
        for (int j = 0; j < 32; ++j) acc[j] = 0.f;
        for (int c = 0; c < 128; ++c) {
            float w = W[o * 128 + c];
            const float4* t4p = (const float4*)&t_lds[c * 68 + rh * 32];
            #pragma unroll
            for (int j4 = 0; j4 < 8; ++j4) {
                float4 t4 = t4p[j4];
                acc[j4*4+0] += t4.x * w;
                acc[j4*4+1] += t4.y * w;
                acc[j4*4+2] += t4.z * w;
                acc[j4*4+3] += t4.w * w;
            }
        }
        float bias = bs[mat][o];
        if (mat == 1) {
            // direct bf16 stores: each thread owns 64B contiguous
            ushort4* kp4 = (ushort4*)(kt_ws + (size_t)(b * CC + o) * NTOK + n0 + rh * 32);
            #pragma unroll
            for (int j8 = 0; j8 < 8; ++j8) {
                ushort4 s;
                s.x = f2bf(acc[j8*4+0] + bias); s.y = f2bf(acc[j8*4+1] + bias);
                s.z = f2bf(acc[j8*4+2] + bias); s.w = f2bf(acc[j8*4+3] + bias);
                kp4[j8] = s;
            }
        } else {
            #pragma unroll
            for (int j = 0; j < 32; ++j)
                st[(rh * 32 + j) * 128 + o] = f2bf(acc[j] + bias);
            __syncthreads();
            u16* gp = (mat == 0 ? q_ws : v_ws) + (size_t)(b * NTOK + n0) * CC;
            const ushort4* s4 = (const ushort4*)st;
            ushort4* g4 = (ushort4*)gp;
            for (int k = tid; k < 2048; k += 256) g4[k] = s4[k];
            __syncthreads();
        }
    }
}

// ---------------- Kernel 2: fused attention, 8 rows/block, 512 threads -----
__global__ __launch_bounds__(512) void attn_kernel(
    const u16* __restrict__ q_ws, const u16* __restrict__ kt_ws,
    const u16* __restrict__ v_ws, float* __restrict__ xs_ws)
{
    __shared__ float qi[128 * 8];        // [c][r] fp32
    __shared__ u16   sp[8 * NTOK];       // [r][m] scores -> p (bf16), 36.9KB
    __shared__ float outp[2 * 8 * 128];  // [half][r][c]
    __shared__ float rowinv[8];
    int tid = threadIdx.x;
    int blk = blockIdx.x;
    int b  = blk & 7;                    // XCD swizzle: one batch per XCD
    int n0 = (blk >> 3) * 8;
    int lane = tid & 63, wid = tid >> 6;

    // Phase A: stage 8 Q rows as fp32 [c][r]
    for (int k = tid; k < 1024; k += 512) {
        int r = k >> 7, c = k & 127;
        qi[c * 8 + r] = bf2f(q_ws[(size_t)(b * NTOK + n0 + r) * CC + c]);
    }
    __syncthreads();

    const float scale = 0.08838834764831845f;  // 1/sqrt(128)
    const u16* ktb = kt_ws + (size_t)b * CC * NTOK;

    // Phase B: S = Q K^T * scale. Main: thread -> 4 consecutive m (0..2047).
    {
        int m = tid * 4;
        float acc[8][4];
        #pragma unroll
        for (int r = 0; r < 8; ++r)
            #pragma unroll
            for (int mm = 0; mm < 4; ++mm) acc[r][mm] = 0.f;
        for (int c = 0; c < 128; ++c) {
            ushort4 k4 = *(const ushort4*)&ktb[(size_t)c * NTOK + m];
            float kf0 = bf2f(k4.x), kf1 = bf2f(k4.y), kf2 = bf2f(k4.z), kf3 = bf2f(k4.w);
            float4 qa = *(const float4*)&qi[c * 8];
            float4 qb = *(const float4*)&qi[c * 8 + 4];
            float qr[8] = {qa.x, qa.y, qa.z, qa.w, qb.x, qb.y, qb.z, qb.w};
            #pragma unroll
            for (int r = 0; r < 8; ++r) {
                acc[r][0] += qr[r] * kf0;
                acc[r][1] += qr[r] * kf1;
                acc[r][2] += qr[r] * kf2;
                acc[r][3] += qr[r] * kf3;
            }
        }
        #pragma unroll
        for (int r = 0; r < 8; ++r) {
            ushort4 s4;
            s4.x = f2bf(acc[r][0] * scale); s4.y = f2bf(acc[r][1] * scale);
            s4.z = f2bf(acc[r][2] * scale); s4.w = f2bf(acc[r][3] * scale);
            *(ushort4*)&sp[r * NTOK + m] = s4;
        }
    }
    // Extra m 2048..2303: 32 per wave (lanes 0..31), spread across all waves
    if ((lane & 63) < 32) {
        int me = 2048 + wid * 32 + lane;
        float acc2[8];
        #pragma unroll
        for (int r = 0; r < 8; ++r) acc2[r] = 0.f;
        for (int c = 0; c < 128; ++c) {
            float kf = bf2f(ktb[(size_t)c * NTOK + me]);
            float4 qa = *(const float4*)&qi[c * 8];
            float4 qb = *(const float4*)&qi[c * 8 + 4];
            acc2[0] += qa.x * kf; acc2[1] += qa.y * kf;
            acc2[2] += qa.z * kf; acc2[3] += qa.w * kf;
            acc2[4] += qb.x * kf; acc2[5] += qb.y * kf;
            acc2[6] += qb.z * kf; acc2[7] += qb.w * kf;
        }
        #pragma unroll
        for (int r = 0; r < 8; ++r) sp[r * NTOK + me] = f2bf(acc2[r] * scale);
    }
    __syncthreads();

    // Phase C: per-wave exact top-k threshold on 16-bit monotone keys
    u16* srow = &sp[wid * NTOK];
    int keys[36];
    float vmax = -1e30f;
    #pragma unroll
    for (int j = 0; j < 36; ++j) {
        int m = lane + j * 64;
        u16 raw = srow[m];
        u32 key = (raw & 0x8000u) ? (u32)(0xFFFFu & ~(u32)raw) : (u32)(raw | 0x8000u);
        keys[j] = (int)key;
        vmax = fmaxf(vmax, bf2f(raw));
    }
    #pragma unroll
    for (int off = 32; off; off >>= 1) vmax = fmaxf(vmax, __shfl_xor(vmax, off, 64));
    u32 res = 0;
    for (int bit = 15; bit >= 0; --bit) {
        int cand = (int)(res | (1u << bit));
        int cnt = 0;
        #pragma unroll
        for (int j = 0; j < 36; ++j) cnt += (keys[j] >= cand) ? 1 : 0;
        #pragma unroll
        for (int off = 32; off; off >>= 1) cnt += __shfl_xor(cnt, off, 64);
        if (cnt >= KTOP) res = (u32)cand;
    }
    // Phase D: masked exp, write p (bf16) back over scores
    float lsum = 0.f;
    #pragma unroll
    for (int j = 0; j < 36; ++j) {
        int m = lane + j * 64;
        float e = 0.f;
        if ((u32)keys[j] >= res) e = __expf(bf2f(srow[m]) - vmax);
        srow[m] = f2bf(e);
        lsum += e;
    }
    #pragma unroll
    for (int off = 32; off; off >>= 1) lsum += __shfl_xor(lsum, off, 64);
    if (lane == 0) rowinv[wid] = 1.f / lsum;
    __syncthreads();

    // Phase E: out[r][c] = sum_m p[r][m] * V[m][c]; thread = (r, half, c4)
    {
        int c4 = tid & 31;
        int half = (tid >> 5) & 1;
        int r = tid >> 6;
        const u16* vb = v_ws + (size_t)b * NTOK * CC + c4 * 4;
        const u16* prow = &sp[r * NTOK];
        float a0 = 0.f, a1 = 0.f, a2 = 0.f, a3 = 0.f;
        int m0 = half * 1152;
        for (int m = m0; m < m0 + 1152; m += 4) {
            ushort4 p4 = *(const ushort4*)&prow[m];
            float pf0 = bf2f(p4.x), pf1 = bf2f(p4.y), pf2 = bf2f(p4.z), pf3 = bf2f(p4.w);
            ushort4 v0 = *(const ushort4*)&vb[(size_t)(m + 0) * CC];
            ushort4 v1 = *(const ushort4*)&vb[(size_t)(m + 1) * CC];
            ushort4 v2 = *(const ushort4*)&vb[(size_t)(m + 2) * CC];
            ushort4 v3 = *(const ushort4*)&vb[(size_t)(m + 3) * CC];
            a0 += pf0 * bf2f(v0.x) + pf1 * bf2f(v1.x) + pf2 * bf2f(v2.x) + pf3 * bf2f(v3.x);
            a1 += pf0 * bf2f(v0.y) + pf1 * bf2f(v1.y) + pf2 * bf2f(v2.y) + pf3 * bf2f(v3.y);
            a2 += pf0 * bf2f(v0.z) + pf1 * bf2f(v1.z) + pf2 * bf2f(v2.z) + pf3 * bf2f(v3.z);
            a3 += pf0 * bf2f(v0.w) + pf1 * bf2f(v1.w) + pf2 * bf2f(v2.w) + pf3 * bf2f(v3.w);
        }
        float4 stv = {a0, a1, a2, a3};
        *(float4*)&outp[(half * 8 + r) * 128 + c4 * 4] = stv;
    }
    __syncthreads();
    if (tid < 256) {
        int r = tid >> 5, c4 = tid & 31;
        float4 A = *(const float4*)&outp[r * 128 + c4 * 4];
        float4 Bv = *(const float4*)&outp[(8 + r) * 128 + c4 * 4];
        float inv = rowinv[r];
        float4 o4 = {(A.x + Bv.x) * inv, (A.y + Bv.y) * inv,
                     (A.z + Bv.z) * inv, (A.w + Bv.w) * inv};
        *(float4*)&xs_ws[(size_t)(b * NTOK + n0 + r) * CC + c4 * 4] = o4;
    }
}

// ---------------- Kernel 3: gate conv + sigmoid ----------------------------
// block = (b, 64-pixel group); 4 channel-quarters per pixel, LDS reduce.
__global__ __launch_bounds__(256) void gate_kernel(
    const float* __restrict__ xs_ws, const float* __restrict__ gw,
    const float* __restrict__ gb, float* __restrict__ imp_ws)
{
    __shared__ float gsum[256];
    int blk = blockIdx.x;
    int b  = blk & 7;
    int p0 = (blk >> 3) * 64;
    int tid = threadIdx.x;
    int pl = tid & 63, cq = tid >> 6;
    int p = p0 + pl;
    int h = p / 48, w = p % 48;
    float acc = 0.f;
    const float* xb = xs_ws + (size_t)b * CC * NTOK;
    for (int i = cq * 32; i < cq * 32 + 32; ++i) {
        const float* plane = xb + (size_t)i * NTOK;
        const float* wv = gw + i * 9;
        #pragma unroll
        for (int kh = 0; kh < 3; ++kh) {
            int hh = h + kh - 1;
            if ((unsigned)hh >= 48u) continue;
            #pragma unroll
            for (int kw = 0; kw < 3; ++kw) {
                int ww = w + kw - 1;
                if ((unsigned)ww >= 48u) continue;
                acc += plane[hh * 48 + ww] * wv[kh * 3 + kw];
            }
        }
    }
    gsum[cq * 64 + pl] = acc;
    __syncthreads();
    if (tid < 64) {
        float s = gsum[tid] + gsum[64 + tid] + gsum[128 + tid] + gsum[192 + tid] + gb[0];
        imp_ws[b * NTOK + p0 + tid] = 1.f / (1.f + __expf(-s));
    }
}

// ---------------- Kernel 4: ref conv (gated) + residual + temporal ---------
// block = (b, 2 output channels); thread = 3x3 output tile (25 LDS reads).
__global__ __launch_bounds__(256) void refconv_kernel(
    const float* __restrict__ xs_ws, const float* __restrict__ imp_ws,
    const float* __restrict__ rw, const float* __restrict__ rb,
    const float* __restrict__ prev, float* __restrict__ xs2_ws)
{
    __shared__ float plane[50 * 50];
    __shared__ float imp_l[NTOK];
    int blk = blockIdx.x;
    int b  = blk & 7;
    int o0 = (blk >> 3) * 2;
    int tid = threadIdx.x;
    for (int k = tid; k < NTOK; k += 256) imp_l[k] = imp_ws[b * NTOK + k];
    int r0 = (tid >> 4) * 3, c0 = (tid & 15) * 3;
    float acc[2][9];
    #pragma unroll
    for (int k = 0; k < 2; ++k)
        #pragma unroll
        for (int q = 0; q < 9; ++q) acc[k][q] = 0.f;
    const float* xb = xs_ws + (size_t)b * CC * NTOK;
    __syncthreads();
    for (int i = 0; i < 128; ++i) {
        for (int idx = tid; idx < 2500; idx += 256) {
            int r = idx / 50, c = idx % 50;
            int h = r - 1, w = c - 1;
            float v = 0.f;
            if ((unsigned)h < 48u && (unsigned)w < 48u) {
                int pp = h * 48 + w;
                v = xb[(size_t)i * NTOK + pp] * imp_l[pp];
            }
            plane[idx] = v;
        }
        __syncthreads();
        float w0[9], w1[9];
        const float* wp0 = rw + ((size_t)o0 * 128 + i) * 9;
        const float* wp1 = rw + ((size_t)(o0 + 1) * 128 + i) * 9;
        #pragma unroll
        for (int k = 0; k < 9; ++k) { w0[k] = wp0[k]; w1[k] = wp1[k]; }
        float win[5][5];
        #pragma unroll
        for (int ii = 0; ii < 5; ++ii)
            #pragma unroll
            for (int jj = 0; jj < 5; ++jj)
                win[ii][jj] = plane[(r0 + ii) * 50 + c0 + jj];
        #pragma unroll
        for (int oi = 0; oi < 3; ++oi)
            #pragma unroll
            for (int oj = 0; oj < 3; ++oj) {
                float s0 = 0.f, s1 = 0.f;
                #pragma unroll
                for (int ki = 0; ki < 3; ++ki)
                    #pragma unroll
                    for (int kj = 0; kj < 3; ++kj) {
                        float t = win[oi + ki][oj + kj];
                        s0 += t * w0[ki * 3 + kj];
                        s1 += t * w1[ki * 3 + kj];
                    }
                acc[0][oi * 3 + oj] += s0;
                acc[1][oi * 3 + oj] += s1;
            }
        __syncthreads();
    }
    #pragma unroll
    for (int k = 0; k < 2; ++k) {
        int o = o0 + k;
        float bias = rb[o];
        const float* xso = xs_ws + ((size_t)b * CC + o) * NTOK;
        const float* pv  = prev  + ((size_t)b * CC + o) * NTOK;
        float* op = xs2_ws + ((size_t)b * CC + o) * NTOK;
        #pragma unroll
        for (int oi = 0; oi < 3; ++oi)
            #pragma unroll
            for (int oj = 0; oj < 3; ++oj) {
                int p = (r0 + oi) * 48 + c0 + oj;
                op[p] = acc[k][oi * 3 + oj] + bias + xso[p] + 0.5f * pv[p];
            }
    }
}

// ---------------- Kernel 5: coverage conv (3x3, dil 2) via parity subplanes -
__global__ __launch_bounds__(256) void covconv_kernel(
    const float* __restrict__ xs2_ws, const float* __restrict__ cw,
    const float* __restrict__ cb, float* __restrict__ out)
{
    __shared__ float spl[4 * 26 * 26];  // 4 parity subplanes, halo 1
    int blk = blockIdx.x;
    int b  = blk & 7;
    int o0 = (blk >> 3) * 2;
    int tid = threadIdx.x;
    int par = tid >> 6;         // wave-uniform
    int t = tid & 63;
    int ro0 = (t >> 3) * 3, co0 = (t & 7) * 3;
    int ph = par >> 1, pw = par & 1;
    float acc[2][9];
    #pragma unroll
    for (int k = 0; k < 2; ++k)
        #pragma unroll
        for (int q = 0; q < 9; ++q) acc[k][q] = 0.f;
    const float* xb = xs2_ws + (size_t)b * CC * NTOK;
    const float* base = &spl[par * 676];
    for (int i = 0; i < 128; ++i) {
        for (int idx = tid; idx < 2704; idx += 256) {
            int pq = idx / 676, rem = idx % 676;
            int r = rem / 26, c = rem % 26;
            int h = (r - 1) * 2 + (pq >> 1);
            int w = (c - 1) * 2 + (pq & 1);
            float v = 0.f;
            if ((unsigned)h < 48u && (unsigned)w < 48u)
                v = xb[(size_t)i * NTOK + h * 48 + w];
            spl[idx] = v;
        }
        __syncthreads();
        float w0[9], w1[9];
        const float* wp0 = cw + ((size_t)o0 * 128 + i) * 9;
        const float* wp1 = cw + ((size_t)(o0 + 1) * 128 + i) * 9;
        #pragma unroll
        for (int k = 0; k < 9; ++k) { w0[k] = wp0[k]; w1[k] = wp1[k]; }
        float win[5][5];
        #pragma unroll
        for (int ii = 0; ii < 5; ++ii)
            #pragma unroll
            for (int jj = 0; jj < 5; ++jj)
                win[ii][jj] = base[(ro0 + ii) * 26 + co0 + jj];
        #pragma unroll
        for (int oi = 0; oi < 3; ++oi)
            #pragma unroll
            for (int oj = 0; oj < 3; ++oj) {
                float s0 = 0.f, s1 = 0.f;
                #pragma unroll
                for (int ki = 0; ki < 3; ++ki)
                    #pragma unroll
                    for (int kj = 0; kj < 3; ++kj) {
                        float tv = win[oi + ki][oj + kj];
                        s0 += tv * w0[ki * 3 + kj];
                        s1 += tv * w1[ki * 3 + kj];
                    }
                acc[0][oi * 3 + oj] += s0;
                acc[1][oi * 3 + oj] += s1;
            }
        __syncthreads();
    }
    #pragma unroll
    for (int k = 0; k < 2; ++k) {
        int o = o0 + k;
        float bias = cb[o];
        float* op = out + ((size_t)b * CC + o) * NTOK;
        #pragma unroll
        for (int oi = 0; oi < 3; ++oi)
            #pragma unroll
            for (int oj = 0; oj < 3; ++oj) {
                int h = 2 * (ro0 + oi) + ph;
                int w = 2 * (co0 + oj) + pw;
                op[h * 48 + w] = acc[k][oi * 3 + oj] + bias;
            }
    }
}

extern "C" void kernel_launch(void* const* d_in, const int* in_sizes, int n_in,
                              void* d_out, int out_size, void* d_ws, size_t ws_size,
                              hipStream_t stream)
{
    const float* x    = (const float*)d_in[0];
    const float* prev = (const float*)d_in[1];
    const float* Wq   = (const float*)d_in[2];
    const float* bq   = (const float*)d_in[3];
    const float* Wk   = (const float*)d_in[4];
    const float* bk   = (const float*)d_in[5];
    const float* Wv   = (const float*)d_in[6];
    const float* bv   = (const float*)d_in[7];
    const float* rw   = (const float*)d_in[8];
    const float* rb   = (const float*)d_in[9];
    const float* gw   = (const float*)d_in[10];
    const float* gb   = (const float*)d_in[11];
    const float* cw   = (const float*)d_in[12];
    const float* cb   = (const float*)d_in[13];
    float* out = (float*)d_out;
    char* ws = (char*)d_ws;

    const size_t SZ = (size_t)BB * NTOK * CC;   // 2359296 elements
    u16*   q_ws   = (u16*)(ws);
    u16*   kt_ws  = (u16*)(ws + SZ * 2);
    u16*   v_ws   = (u16*)(ws + SZ * 4);
    float* xs_ws  = (float*)(ws + SZ * 6);
    float* imp_ws = (float*)(ws + SZ * 6 + SZ * 4);
    float* xs2_ws = (float*)(ws + SZ * 6 + SZ * 4 + (size_t)BB * NTOK * 4);
    // total: SZ*10 + B*N*4 + SZ*4 bytes ~= 33 MB

    qkv_kernel<<<dim3(288), dim3(256), 0, stream>>>(x, Wq, bq, Wk, bk, Wv, bv,
                                                    q_ws, kt_ws, v_ws);
    attn_kernel<<<dim3(2304), dim3(512), 0, stream>>>(q_ws, kt_ws, v_ws, xs_ws);
    gate_kernel<<<dim3(288), dim3(256), 0, stream>>>(xs_ws, gw, gb, imp_ws);
    refconv_kernel<<<dim3(512), dim3(256), 0, stream>>>(xs_ws, imp_ws, rw, rb,
                                                        prev, xs2_ws);
    covconv_kernel<<<dim3(512), dim3(256), 0, stream>>>(xs2_ws, cw, cb, out);
}

// Round 3
// 1282.550 us; speedup vs baseline: 1.5802x; 1.3140x over previous
//
#include <hip/hip_runtime.h>
#include <hip/hip_bf16.h>
#include <math.h>

#define BB 8
#define CC 128
#define NTOK 2304   // 48*48
#define KTOP 1843   // int(2304*0.8)

typedef unsigned short u16;
typedef unsigned int   u32;
typedef __attribute__((ext_vector_type(8))) short short8;
typedef __attribute__((ext_vector_type(4))) float f32x4;

static __device__ __forceinline__ float bf2f(u16 u) {
    return __uint_as_float(((u32)u) << 16);
}
static __device__ __forceinline__ u16 f2bf(float f) {
    u32 x = __float_as_uint(f);
    return (u16)((x + 0x7fffu + ((x >> 16) & 1u)) >> 16);  // RNE
}

// ---------------- Kernel 1: QKV projections (bf16 outputs) ----------------
// Q,K: [B,N,C] bf16 (row-major, MFMA-frag friendly); V: [B,C,N] bf16 (transposed).
__global__ __launch_bounds__(256) void qkv_kernel(
    const float* __restrict__ x,
    const float* __restrict__ Wq, const float* __restrict__ bq,
    const float* __restrict__ Wk, const float* __restrict__ bk,
    const float* __restrict__ Wv, const float* __restrict__ bv,
    u16* __restrict__ q_ws, u16* __restrict__ k_ws, u16* __restrict__ v_ws)
{
    __shared__ float t_lds[128 * 68];   // [c][r]
    __shared__ u16 st[64 * 128];        // transpose staging for q/k stores
    int blk = blockIdx.x;
    int b  = blk / 36;
    int n0 = (blk % 36) * 64;
    int tid = threadIdx.x;
    const float* xb = x + (size_t)(b * NTOK + n0) * CC;
    #pragma unroll
    for (int k = 0; k < 32; ++k) {
        int idx = k * 256 + tid;
        t_lds[(idx & 127) * 68 + (idx >> 7)] = xb[idx];
    }
    __syncthreads();
    int o  = tid & 127;
    int rh = tid >> 7;
    const float* Ws[3] = {Wq, Wk, Wv};
    const float* bs[3] = {bq, bk, bv};
    for (int mat = 0; mat < 3; ++mat) {
        const float* W = Ws[mat];
        float acc[32];
        #pragma unroll
        for (int j = 0; j < 32; ++j) acc[j] = 0.f;
        for (int c = 0; c < 128; ++c) {
            float w = W[o * 128 + c];
            const float4* t4p = (const float4*)&t_lds[c * 68 + rh * 32];
            #pragma unroll
            for (int j4 = 0; j4 < 8; ++j4) {
                float4 t4 = t4p[j4];
                acc[j4*4+0] += t4.x * w;
                acc[j4*4+1] += t4.y * w;
                acc[j4*4+2] += t4.z * w;
                acc[j4*4+3] += t4.w * w;
            }
        }
        float bias = bs[mat][o];
        if (mat == 2) {
            // V: direct transposed store [B,C,N]; thread owns 64B contiguous
            ushort4* vp4 = (ushort4*)(v_ws + (size_t)(b * CC + o) * NTOK + n0 + rh * 32);
            #pragma unroll
            for (int j8 = 0; j8 < 8; ++j8) {
                ushort4 s;
                s.x = f2bf(acc[j8*4+0] + bias); s.y = f2bf(acc[j8*4+1] + bias);
                s.z = f2bf(acc[j8*4+2] + bias); s.w = f2bf(acc[j8*4+3] + bias);
                vp4[j8] = s;
            }
        } else {
            // Q/K: [B,N,C] via LDS transpose staging for coalesced stores
            #pragma unroll
            for (int j = 0; j < 32; ++j)
                st[(rh * 32 + j) * 128 + o] = f2bf(acc[j] + bias);
            __syncthreads();
            u16* gp = (mat == 0 ? q_ws : k_ws) + (size_t)(b * NTOK + n0) * CC;
            const ushort4* s4 = (const ushort4*)st;
            ushort4* g4 = (ushort4*)gp;
            for (int k = tid; k < 2048; k += 256) g4[k] = s4[k];
            __syncthreads();
        }
    }
}

// ---------------- Kernel 2: MFMA attention, 16 rows/block, 512 threads -----
// QK^T via mfma_f32_16x16x32_bf16, scores bf16 in LDS (XOR-swizzled),
// exact top-k binary search per row, softmax, PV via MFMA.
__global__ __launch_bounds__(512) void attn_kernel(
    const u16* __restrict__ q_ws, const u16* __restrict__ k_ws,
    const u16* __restrict__ v_ws, float* __restrict__ xs_ws)
{
    __shared__ u16 sp[16 * NTOK];   // 73728 B, row stride 4608 B, XOR swizzle
    __shared__ float rowinv[16];
    int tid  = threadIdx.x;
    int lane = tid & 63, wid = tid >> 6;
    int b  = blockIdx.x & 7;                 // one batch per XCD (L2 locality)
    int n0 = (blockIdx.x >> 3) * 16;
    const float scale = 0.08838834764831845f;  // 1/sqrt(128)

    int fr = lane & 15;        // frag row/col index
    int fg = lane >> 4;        // frag k-group (0..3)

    // A-frags: Q[n0+fr][kc*32 + fg*8 .. +8], 4 chunks, kept in registers
    const u16* qbase = q_ws + (size_t)(b * NTOK + n0 + fr) * CC + fg * 8;
    short8 qa[4];
    #pragma unroll
    for (int kc = 0; kc < 4; ++kc)
        qa[kc] = *(const short8*)(qbase + kc * 32);

    // Phase B: S[q][m] = scale * Q K^T ; 144 m-tiles split across 8 waves
    const u16* kb = k_ws + (size_t)(b * NTOK + fr) * CC + fg * 8;
    for (int t = wid; t < 144; t += 8) {
        int m0 = t * 16;
        f32x4 acc = {0.f, 0.f, 0.f, 0.f};
        const u16* kp = kb + (size_t)m0 * CC;
        #pragma unroll
        for (int kc = 0; kc < 4; ++kc) {
            short8 kf = *(const short8*)(kp + kc * 32);
            acc = __builtin_amdgcn_mfma_f32_16x16x32_bf16(qa[kc], kf, acc, 0, 0, 0);
        }
        int mcol = m0 + fr;
        #pragma unroll
        for (int r = 0; r < 4; ++r) {
            int q = fg * 4 + r;
            sp[q * NTOK + (mcol ^ ((q & 7) << 3))] = f2bf(acc[r] * scale);
        }
    }
    __syncthreads();

    // Phase C+D: exact top-k threshold + masked softmax; wave -> 2 rows
    for (int rr = 0; rr < 2; ++rr) {
        int row = wid * 2 + rr;
        int xorv = (row & 7) << 3;
        u16* srow = sp + row * NTOK;
        int keys[36];
        float vmax = -1e30f;
        #pragma unroll
        for (int j = 0; j < 36; ++j) {
            int m = lane + j * 64;
            u16 raw = srow[m ^ xorv];
            u32 key = (raw & 0x8000u) ? (u32)(0xFFFFu & ~(u32)raw) : (u32)(raw | 0x8000u);
            keys[j] = (int)key;
            vmax = fmaxf(vmax, bf2f(raw));
        }
        #pragma unroll
        for (int off = 32; off; off >>= 1) vmax = fmaxf(vmax, __shfl_xor(vmax, off, 64));
        u32 res = 0;
        for (int bit = 15; bit >= 0; --bit) {
            int cand = (int)(res | (1u << bit));
            int cnt = 0;
            #pragma unroll
            for (int j = 0; j < 36; ++j) cnt += (keys[j] >= cand) ? 1 : 0;
            #pragma unroll
            for (int off = 32; off; off >>= 1) cnt += __shfl_xor(cnt, off, 64);
            if (cnt >= KTOP) res = (u32)cand;
        }
        float lsum = 0.f;
        #pragma unroll
        for (int j = 0; j < 36; ++j) {
            int m = lane + j * 64;
            float e = 0.f;
            if ((u32)keys[j] >= res) e = __expf(bf2f(srow[m ^ xorv]) - vmax);
            srow[m ^ xorv] = f2bf(e);
            lsum += e;
        }
        #pragma unroll
        for (int off = 32; off; off >>= 1) lsum += __shfl_xor(lsum, off, 64);
        if (lane == 0) rowinv[row] = 1.f / lsum;
    }
    __syncthreads();

    // Phase E: out[q][c] = sum_m P[q][m] * V[m][c]; wave -> 16-col tile
    {
        int c0 = wid * 16;
        const u16* vb = v_ws + (size_t)(b * CC + c0 + fr) * NTOK + fg * 8;
        const u16* arow = sp + fr * NTOK;
        int xorv = (fr & 7) << 3;
        f32x4 oacc = {0.f, 0.f, 0.f, 0.f};
        for (int ch = 0; ch < 72; ++ch) {
            int m0 = ch * 32;
            short8 pa = *(const short8*)(arow + ((m0 + fg * 8) ^ xorv));
            short8 vf = *(const short8*)(vb + m0);
            oacc = __builtin_amdgcn_mfma_f32_16x16x32_bf16(pa, vf, oacc, 0, 0, 0);
        }
        #pragma unroll
        for (int r = 0; r < 4; ++r) {
            int q = fg * 4 + r;
            xs_ws[(size_t)(b * NTOK + n0 + q) * CC + c0 + fr] = oacc[r] * rowinv[q];
        }
    }
}

// ---------------- Kernel 3: gate conv + sigmoid ----------------------------
__global__ __launch_bounds__(256) void gate_kernel(
    const float* __restrict__ xs_ws, const float* __restrict__ gw,
    const float* __restrict__ gb, float* __restrict__ imp_ws)
{
    __shared__ float gsum[256];
    int blk = blockIdx.x;
    int b  = blk & 7;
    int p0 = (blk >> 3) * 64;
    int tid = threadIdx.x;
    int pl = tid & 63, cq = tid >> 6;
    int p = p0 + pl;
    int h = p / 48, w = p % 48;
    float acc = 0.f;
    const float* xb = xs_ws + (size_t)b * CC * NTOK;
    for (int i = cq * 32; i < cq * 32 + 32; ++i) {
        const float* plane = xb + (size_t)i * NTOK;
        const float* wv = gw + i * 9;
        #pragma unroll
        for (int kh = 0; kh < 3; ++kh) {
            int hh = h + kh - 1;
            if ((unsigned)hh >= 48u) continue;
            #pragma unroll
            for (int kw = 0; kw < 3; ++kw) {
                int ww = w + kw - 1;
                if ((unsigned)ww >= 48u) continue;
                acc += plane[hh * 48 + ww] * wv[kh * 3 + kw];
            }
        }
    }
    gsum[cq * 64 + pl] = acc;
    __syncthreads();
    if (tid < 64) {
        float s = gsum[tid] + gsum[64 + tid] + gsum[128 + tid] + gsum[192 + tid] + gb[0];
        imp_ws[b * NTOK + p0 + tid] = 1.f / (1.f + __expf(-s));
    }
}

// ---------------- Kernel 4: ref conv (gated) + residual + temporal ---------
__global__ __launch_bounds__(256) void refconv_kernel(
    const float* __restrict__ xs_ws, const float* __restrict__ imp_ws,
    const float* __restrict__ rw, const float* __restrict__ rb,
    const float* __restrict__ prev, float* __restrict__ xs2_ws)
{
    __shared__ float plane[50 * 50];
    __shared__ float imp_l[NTOK];
    int blk = blockIdx.x;
    int b  = blk & 7;
    int o0 = (blk >> 3) * 2;
    int tid = threadIdx.x;
    for (int k = tid; k < NTOK; k += 256) imp_l[k] = imp_ws[b * NTOK + k];
    int r0 = (tid >> 4) * 3, c0 = (tid & 15) * 3;
    float acc[2][9];
    #pragma unroll
    for (int k = 0; k < 2; ++k)
        #pragma unroll
        for (int q = 0; q < 9; ++q) acc[k][q] = 0.f;
    const float* xb = xs_ws + (size_t)b * CC * NTOK;
    __syncthreads();
    for (int i = 0; i < 128; ++i) {
        for (int idx = tid; idx < 2500; idx += 256) {
            int r = idx / 50, c = idx % 50;
            int h = r - 1, w = c - 1;
            float v = 0.f;
            if ((unsigned)h < 48u && (unsigned)w < 48u) {
                int pp = h * 48 + w;
                v = xb[(size_t)i * NTOK + pp] * imp_l[pp];
            }
            plane[idx] = v;
        }
        __syncthreads();
        float w0[9], w1[9];
        const float* wp0 = rw + ((size_t)o0 * 128 + i) * 9;
        const float* wp1 = rw + ((size_t)(o0 + 1) * 128 + i) * 9;
        #pragma unroll
        for (int k = 0; k < 9; ++k) { w0[k] = wp0[k]; w1[k] = wp1[k]; }
        float win[5][5];
        #pragma unroll
        for (int ii = 0; ii < 5; ++ii)
            #pragma unroll
            for (int jj = 0; jj < 5; ++jj)
                win[ii][jj] = plane[(r0 + ii) * 50 + c0 + jj];
        #pragma unroll
        for (int oi = 0; oi < 3; ++oi)
            #pragma unroll
            for (int oj = 0; oj < 3; ++oj) {
                float s0 = 0.f, s1 = 0.f;
                #pragma unroll
                for (int ki = 0; ki < 3; ++ki)
                    #pragma unroll
                    for (int kj = 0; kj < 3; ++kj) {
                        float t = win[oi + ki][oj + kj];
                        s0 += t * w0[ki * 3 + kj];
                        s1 += t * w1[ki * 3 + kj];
                    }
                acc[0][oi * 3 + oj] += s0;
                acc[1][oi * 3 + oj] += s1;
            }
        __syncthreads();
    }
    #pragma unroll
    for (int k = 0; k < 2; ++k) {
        int o = o0 + k;
        float bias = rb[o];
        const float* xso = xs_ws + ((size_t)b * CC + o) * NTOK;
        const float* pv  = prev  + ((size_t)b * CC + o) * NTOK;
        float* op = xs2_ws + ((size_t)b * CC + o) * NTOK;
        #pragma unroll
        for (int oi = 0; oi < 3; ++oi)
            #pragma unroll
            for (int oj = 0; oj < 3; ++oj) {
                int p = (r0 + oi) * 48 + c0 + oj;
                op[p] = acc[k][oi * 3 + oj] + bias + xso[p] + 0.5f * pv[p];
            }
    }
}

// ---------------- Kernel 5: coverage conv (3x3, dil 2) via parity subplanes -
__global__ __launch_bounds__(256) void covconv_kernel(
    const float* __restrict__ xs2_ws, const float* __restrict__ cw,
    const float* __restrict__ cb, float* __restrict__ out)
{
    __shared__ float spl[4 * 26 * 26];
    int blk = blockIdx.x;
    int b  = blk & 7;
    int o0 = (blk >> 3) * 2;
    int tid = threadIdx.x;
    int par = tid >> 6;
    int t = tid & 63;
    int ro0 = (t >> 3) * 3, co0 = (t & 7) * 3;
    int ph = par >> 1, pw = par & 1;
    float acc[2][9];
    #pragma unroll
    for (int k = 0; k < 2; ++k)
        #pragma unroll
        for (int q = 0; q < 9; ++q) acc[k][q] = 0.f;
    const float* xb = xs2_ws + (size_t)b * CC * NTOK;
    const float* base = &spl[par * 676];
    for (int i = 0; i < 128; ++i) {
        for (int idx = tid; idx < 2704; idx += 256) {
            int pq = idx / 676, rem = idx % 676;
            int r = rem / 26, c = rem % 26;
            int h = (r - 1) * 2 + (pq >> 1);
            int w = (c - 1) * 2 + (pq & 1);
            float v = 0.f;
            if ((unsigned)h < 48u && (unsigned)w < 48u)
                v = xb[(size_t)i * NTOK + h * 48 + w];
            spl[idx] = v;
        }
        __syncthreads();
        float w0[9], w1[9];
        const float* wp0 = cw + ((size_t)o0 * 128 + i) * 9;
        const float* wp1 = cw + ((size_t)(o0 + 1) * 128 + i) * 9;
        #pragma unroll
        for (int k = 0; k < 9; ++k) { w0[k] = wp0[k]; w1[k] = wp1[k]; }
        float win[5][5];
        #pragma unroll
        for (int ii = 0; ii < 5; ++ii)
            #pragma unroll
            for (int jj = 0; jj < 5; ++jj)
                win[ii][jj] = base[(ro0 + ii) * 26 + co0 + jj];
        #pragma unroll
        for (int oi = 0; oi < 3; ++oi)
            #pragma unroll
            for (int oj = 0; oj < 3; ++oj) {
                float s0 = 0.f, s1 = 0.f;
                #pragma unroll
                for (int ki = 0; ki < 3; ++ki)
                    #pragma unroll
                    for (int kj = 0; kj < 3; ++kj) {
                        float tv = win[oi + ki][oj + kj];
                        s0 += tv * w0[ki * 3 + kj];
                        s1 += tv * w1[ki * 3 + kj];
                    }
                acc[0][oi * 3 + oj] += s0;
                acc[1][oi * 3 + oj] += s1;
            }
        __syncthreads();
    }
    #pragma unroll
    for (int k = 0; k < 2; ++k) {
        int o = o0 + k;
        float bias = cb[o];
        float* op = out + ((size_t)b * CC + o) * NTOK;
        #pragma unroll
        for (int oi = 0; oi < 3; ++oi)
            #pragma unroll
            for (int oj = 0; oj < 3; ++oj) {
                int h = 2 * (ro0 + oi) + ph;
                int w = 2 * (co0 + oj) + pw;
                op[h * 48 + w] = acc[k][oi * 3 + oj] + bias;
            }
    }
}

extern "C" void kernel_launch(void* const* d_in, const int* in_sizes, int n_in,
                              void* d_out, int out_size, void* d_ws, size_t ws_size,
                              hipStream_t stream)
{
    const float* x    = (const float*)d_in[0];
    const float* prev = (const float*)d_in[1];
    const float* Wq   = (const float*)d_in[2];
    const float* bq   = (const float*)d_in[3];
    const float* Wk   = (const float*)d_in[4];
    const float* bk   = (const float*)d_in[5];
    const float* Wv   = (const float*)d_in[6];
    const float* bv   = (const float*)d_in[7];
    const float* rw   = (const float*)d_in[8];
    const float* rb   = (const float*)d_in[9];
    const float* gw   = (const float*)d_in[10];
    const float* gb   = (const float*)d_in[11];
    const float* cw   = (const float*)d_in[12];
    const float* cb   = (const float*)d_in[13];
    float* out = (float*)d_out;
    char* ws = (char*)d_ws;

    const size_t SZ = (size_t)BB * NTOK * CC;   // 2359296 elements
    u16*   q_ws   = (u16*)(ws);
    u16*   k_ws   = (u16*)(ws + SZ * 2);
    u16*   v_ws   = (u16*)(ws + SZ * 4);
    float* xs_ws  = (float*)(ws + SZ * 6);
    float* imp_ws = (float*)(ws + SZ * 6 + SZ * 4);
    float* xs2_ws = (float*)(ws + SZ * 6 + SZ * 4 + (size_t)BB * NTOK * 4);

    qkv_kernel<<<dim3(288), dim3(256), 0, stream>>>(x, Wq, bq, Wk, bk, Wv, bv,
                                                    q_ws, k_ws, v_ws);
    attn_kernel<<<dim3(1152), dim3(512), 0, stream>>>(q_ws, k_ws, v_ws, xs_ws);
    gate_kernel<<<dim3(288), dim3(256), 0, stream>>>(xs_ws, gw, gb, imp_ws);
    refconv_kernel<<<dim3(512), dim3(256), 0, stream>>>(xs_ws, imp_ws, rw, rb,
                                                        prev, xs2_ws);
    covconv_kernel<<<dim3(512), dim3(256), 0, stream>>>(xs2_ws, cw, cb, out);
}

// Round 4
// 586.463 us; speedup vs baseline: 3.4558x; 2.1869x over previous
//
#include <hip/hip_runtime.h>
#include <hip/hip_bf16.h>
#include <math.h>

#define BB 8
#define CC 128
#define NTOK 2304   // 48*48
#define KTOP 1843   // int(2304*0.8)

typedef unsigned short u16;
typedef unsigned int   u32;
typedef __attribute__((ext_vector_type(8))) short short8;
typedef __attribute__((ext_vector_type(4))) float f32x4;

static __device__ __forceinline__ float bf2f(u16 u) {
    return __uint_as_float(((u32)u) << 16);
}
static __device__ __forceinline__ u16 f2bf(float f) {
    u32 x = __float_as_uint(f);
    return (u16)((x + 0x7fffu + ((x >> 16) & 1u)) >> 16);  // RNE
}

// ---------------- Kernel 1: QKV projections (bf16 outputs) ----------------
// Q,K: [B,N,C] bf16 (row-major, MFMA-frag friendly); V: [B,C,N] bf16 (transposed).
__global__ __launch_bounds__(256) void qkv_kernel(
    const float* __restrict__ x,
    const float* __restrict__ Wq, const float* __restrict__ bq,
    const float* __restrict__ Wk, const float* __restrict__ bk,
    const float* __restrict__ Wv, const float* __restrict__ bv,
    u16* __restrict__ q_ws, u16* __restrict__ k_ws, u16* __restrict__ v_ws)
{
    __shared__ float t_lds[128 * 68];   // [c][r]
    __shared__ u16 st[64 * 128];        // transpose staging for q/k stores
    int blk = blockIdx.x;
    int b  = blk / 36;
    int n0 = (blk % 36) * 64;
    int tid = threadIdx.x;
    const float* xb = x + (size_t)(b * NTOK + n0) * CC;
    #pragma unroll
    for (int k = 0; k < 32; ++k) {
        int idx = k * 256 + tid;
        t_lds[(idx & 127) * 68 + (idx >> 7)] = xb[idx];
    }
    __syncthreads();
    int o  = tid & 127;
    int rh = tid >> 7;
    const float* Ws[3] = {Wq, Wk, Wv};
    const float* bs[3] = {bq, bk, bv};
    for (int mat = 0; mat < 3; ++mat) {
        const float* W = Ws[mat];
        float acc[32];
        #pragma unroll
        for (int j = 0; j < 32; ++j) acc[j] = 0.f;
        for (int c = 0; c < 128; ++c) {
            float w = W[o * 128 + c];
            const float4* t4p = (const float4*)&t_lds[c * 68 + rh * 32];
            #pragma unroll
            for (int j4 = 0; j4 < 8; ++j4) {
                float4 t4 = t4p[j4];
                acc[j4*4+0] += t4.x * w;
                acc[j4*4+1] += t4.y * w;
                acc[j4*4+2] += t4.z * w;
                acc[j4*4+3] += t4.w * w;
            }
        }
        float bias = bs[mat][o];
        if (mat == 2) {
            ushort4* vp4 = (ushort4*)(v_ws + (size_t)(b * CC + o) * NTOK + n0 + rh * 32);
            #pragma unroll
            for (int j8 = 0; j8 < 8; ++j8) {
                ushort4 s;
                s.x = f2bf(acc[j8*4+0] + bias); s.y = f2bf(acc[j8*4+1] + bias);
                s.z = f2bf(acc[j8*4+2] + bias); s.w = f2bf(acc[j8*4+3] + bias);
                vp4[j8] = s;
            }
        } else {
            #pragma unroll
            for (int j = 0; j < 32; ++j)
                st[(rh * 32 + j) * 128 + o] = f2bf(acc[j] + bias);
            __syncthreads();
            u16* gp = (mat == 0 ? q_ws : k_ws) + (size_t)(b * NTOK + n0) * CC;
            const ushort4* s4 = (const ushort4*)st;
            ushort4* g4 = (ushort4*)gp;
            for (int k = tid; k < 2048; k += 256) g4[k] = s4[k];
            __syncthreads();
        }
    }
}

// ---------------- Kernel 2: MFMA attention, 16 rows/block, 512 threads -----
__global__ __launch_bounds__(512) void attn_kernel(
    const u16* __restrict__ q_ws, const u16* __restrict__ k_ws,
    const u16* __restrict__ v_ws, float* __restrict__ xs_ws)
{
    __shared__ u16 sp[16 * NTOK];   // XOR-swizzled
    __shared__ float rowinv[16];
    int tid  = threadIdx.x;
    int lane = tid & 63, wid = tid >> 6;
    int b  = blockIdx.x & 7;
    int n0 = (blockIdx.x >> 3) * 16;
    const float scale = 0.08838834764831845f;

    int fr = lane & 15;
    int fg = lane >> 4;

    const u16* qbase = q_ws + (size_t)(b * NTOK + n0 + fr) * CC + fg * 8;
    short8 qa[4];
    #pragma unroll
    for (int kc = 0; kc < 4; ++kc)
        qa[kc] = *(const short8*)(qbase + kc * 32);

    const u16* kb = k_ws + (size_t)(b * NTOK + fr) * CC + fg * 8;
    for (int t = wid; t < 144; t += 8) {
        int m0 = t * 16;
        f32x4 acc = {0.f, 0.f, 0.f, 0.f};
        const u16* kp = kb + (size_t)m0 * CC;
        #pragma unroll
        for (int kc = 0; kc < 4; ++kc) {
            short8 kf = *(const short8*)(kp + kc * 32);
            acc = __builtin_amdgcn_mfma_f32_16x16x32_bf16(qa[kc], kf, acc, 0, 0, 0);
        }
        int mcol = m0 + fr;
        #pragma unroll
        for (int r = 0; r < 4; ++r) {
            int q = fg * 4 + r;
            sp[q * NTOK + (mcol ^ ((q & 7) << 3))] = f2bf(acc[r] * scale);
        }
    }
    __syncthreads();

    for (int rr = 0; rr < 2; ++rr) {
        int row = wid * 2 + rr;
        int xorv = (row & 7) << 3;
        u16* srow = sp + row * NTOK;
        int keys[36];
        float vmax = -1e30f;
        #pragma unroll
        for (int j = 0; j < 36; ++j) {
            int m = lane + j * 64;
            u16 raw = srow[m ^ xorv];
            u32 key = (raw & 0x8000u) ? (u32)(0xFFFFu & ~(u32)raw) : (u32)(raw | 0x8000u);
            keys[j] = (int)key;
            vmax = fmaxf(vmax, bf2f(raw));
        }
        #pragma unroll
        for (int off = 32; off; off >>= 1) vmax = fmaxf(vmax, __shfl_xor(vmax, off, 64));
        u32 res = 0;
        for (int bit = 15; bit >= 0; --bit) {
            int cand = (int)(res | (1u << bit));
            int cnt = 0;
            #pragma unroll
            for (int j = 0; j < 36; ++j) cnt += (keys[j] >= cand) ? 1 : 0;
            #pragma unroll
            for (int off = 32; off; off >>= 1) cnt += __shfl_xor(cnt, off, 64);
            if (cnt >= KTOP) res = (u32)cand;
        }
        float lsum = 0.f;
        #pragma unroll
        for (int j = 0; j < 36; ++j) {
            int m = lane + j * 64;
            float e = 0.f;
            if ((u32)keys[j] >= res) e = __expf(bf2f(srow[m ^ xorv]) - vmax);
            srow[m ^ xorv] = f2bf(e);
            lsum += e;
        }
        #pragma unroll
        for (int off = 32; off; off >>= 1) lsum += __shfl_xor(lsum, off, 64);
        if (lane == 0) rowinv[row] = 1.f / lsum;
    }
    __syncthreads();

    {
        int c0 = wid * 16;
        const u16* vb = v_ws + (size_t)(b * CC + c0 + fr) * NTOK + fg * 8;
        const u16* arow = sp + fr * NTOK;
        int xorv = (fr & 7) << 3;
        f32x4 oacc = {0.f, 0.f, 0.f, 0.f};
        for (int ch = 0; ch < 72; ++ch) {
            int m0 = ch * 32;
            short8 pa = *(const short8*)(arow + ((m0 + fg * 8) ^ xorv));
            short8 vf = *(const short8*)(vb + m0);
            oacc = __builtin_amdgcn_mfma_f32_16x16x32_bf16(pa, vf, oacc, 0, 0, 0);
        }
        #pragma unroll
        for (int r = 0; r < 4; ++r) {
            int q = fg * 4 + r;
            xs_ws[(size_t)(b * NTOK + n0 + q) * CC + c0 + fr] = oacc[r] * rowinv[q];
        }
    }
}

// ---------------- Kernel 3: gate conv + sigmoid ----------------------------
__global__ __launch_bounds__(256) void gate_kernel(
    const float* __restrict__ xs_ws, const float* __restrict__ gw,
    const float* __restrict__ gb, float* __restrict__ imp_ws)
{
    __shared__ float gsum[256];
    int blk = blockIdx.x;
    int b  = blk & 7;
    int p0 = (blk >> 3) * 64;
    int tid = threadIdx.x;
    int pl = tid & 63, cq = tid >> 6;
    int p = p0 + pl;
    int h = p / 48, w = p % 48;
    float acc = 0.f;
    const float* xb = xs_ws + (size_t)b * CC * NTOK;
    for (int i = cq * 32; i < cq * 32 + 32; ++i) {
        const float* plane = xb + (size_t)i * NTOK;
        const float* wv = gw + i * 9;
        #pragma unroll
        for (int kh = 0; kh < 3; ++kh) {
            int hh = h + kh - 1;
            if ((unsigned)hh >= 48u) continue;
            #pragma unroll
            for (int kw = 0; kw < 3; ++kw) {
                int ww = w + kw - 1;
                if ((unsigned)ww >= 48u) continue;
                acc += plane[hh * 48 + ww] * wv[kh * 3 + kw];
            }
        }
    }
    gsum[cq * 64 + pl] = acc;
    __syncthreads();
    if (tid < 64) {
        float s = gsum[tid] + gsum[64 + tid] + gsum[128 + tid] + gsum[192 + tid] + gb[0];
        imp_ws[b * NTOK + p0 + tid] = 1.f / (1.f + __expf(-s));
    }
}

// ---------------- Kernel 3b: weight transform -> wb[tap][o][c] bf16 --------
__global__ __launch_bounds__(256) void wtrans_kernel(
    const float* __restrict__ rw, const float* __restrict__ cw,
    u16* __restrict__ wb_ref, u16* __restrict__ wb_cov)
{
    int idx = blockIdx.x * 256 + threadIdx.x;     // 0..294911
    int which = idx >= 147456;
    int rem = which ? idx - 147456 : idx;
    int tap = rem >> 14;                           // /16384
    int rest = rem & 16383;
    int o = rest >> 7, c = rest & 127;
    const float* src = which ? cw : rw;
    u16* dst = which ? wb_cov : wb_ref;
    dst[rem] = f2bf(src[(o * 128 + c) * 9 + tap]);
}

// ---------------- Kernel 3c: transpose to pixel-major + residual buffer ----
// xt_g[b][p][c] = bf16(xs_conv(c,p) * imp[p]); rbuf[b][p][c] = xs + 0.5*prev.
__global__ __launch_bounds__(256) void tpos_kernel(
    const float* __restrict__ xs_ws, const float* __restrict__ prev,
    const float* __restrict__ imp_ws,
    u16* __restrict__ xt_g, float* __restrict__ rbuf)
{
    __shared__ float tx[128 * 65];
    __shared__ float tp[128 * 65];
    int blk = blockIdx.x;
    int b  = blk & 7;
    int p0 = (blk >> 3) * 64;
    int tid = threadIdx.x;
    const float* xsb = xs_ws + (size_t)b * CC * NTOK + p0;
    const float* pvb = prev  + (size_t)b * CC * NTOK + p0;
    #pragma unroll
    for (int it = 0; it < 32; ++it) {
        int idx = it * 256 + tid;
        int i = idx >> 6, pp = idx & 63;
        tx[i * 65 + pp] = xsb[(size_t)i * NTOK + pp];
        tp[i * 65 + pp] = pvb[(size_t)i * NTOK + pp];
    }
    __syncthreads();
    int pl = tid & 63, cq = tid >> 6;
    float impv = imp_ws[b * NTOK + p0 + pl];
    size_t obase = ((size_t)b * NTOK + p0 + pl) * CC + cq * 32;
    u16* gout = xt_g + obase;
    float* rout = rbuf + obase;
    #pragma unroll
    for (int j4 = 0; j4 < 8; ++j4) {
        float4 rv; ushort4 gv;
        float v0 = tx[(cq * 32 + j4 * 4 + 0) * 65 + pl];
        float v1 = tx[(cq * 32 + j4 * 4 + 1) * 65 + pl];
        float v2 = tx[(cq * 32 + j4 * 4 + 2) * 65 + pl];
        float v3 = tx[(cq * 32 + j4 * 4 + 3) * 65 + pl];
        float q0 = tp[(cq * 32 + j4 * 4 + 0) * 65 + pl];
        float q1 = tp[(cq * 32 + j4 * 4 + 1) * 65 + pl];
        float q2 = tp[(cq * 32 + j4 * 4 + 2) * 65 + pl];
        float q3 = tp[(cq * 32 + j4 * 4 + 3) * 65 + pl];
        rv.x = v0 + 0.5f * q0; rv.y = v1 + 0.5f * q1;
        rv.z = v2 + 0.5f * q2; rv.w = v3 + 0.5f * q3;
        gv.x = f2bf(v0 * impv); gv.y = f2bf(v1 * impv);
        gv.z = f2bf(v2 * impv); gv.w = f2bf(v3 * impv);
        *(float4*)(rout + j4 * 4) = rv;
        *(ushort4*)(gout + j4 * 4) = gv;
    }
}

// ---------------- Kernel 4: refinement conv as implicit MFMA GEMM ----------
// out(p,o) = sum_tap sum_c xt_g[p_shift][c] * wb_ref[tap][o][c]; epilogue adds
// bias + rbuf, writes bf16 xt2[p][o].
__global__ __launch_bounds__(256) void refgemm_kernel(
    const u16* __restrict__ xt_g, const u16* __restrict__ wb_ref,
    const float* __restrict__ rbuf, const float* __restrict__ rb,
    u16* __restrict__ xt2)
{
    __shared__ u16 slab[144 * 128];   // XOR-swizzled shifted input slab
    int tid = threadIdx.x;
    int lane = tid & 63, wid = tid >> 6;
    int blk = blockIdx.x;
    int b  = blk & 7;
    int st = (blk >> 3) & 15;
    int oh = blk >> 7;
    int h0 = st * 3;
    int p0g = st * 144;
    int fr = lane & 15, fg = lane >> 4;
    int o0 = oh * 64 + wid * 16;
    const u16* xb = xt_g + (size_t)b * NTOK * CC;

    f32x4 acc[9];
    #pragma unroll
    for (int pt = 0; pt < 9; ++pt) acc[pt] = (f32x4){0.f, 0.f, 0.f, 0.f};

    for (int tap = 0; tap < 9; ++tap) {
        int dh = tap / 3 - 1, dw = tap % 3 - 1;
        __syncthreads();
        #pragma unroll
        for (int it = 0; it < 9; ++it) {
            int idx = it * 256 + tid;          // 0..2303
            int pr = idx >> 4, cv = idx & 15;
            int r = pr >= 96 ? 2 : (pr >= 48 ? 1 : 0);
            int w = pr - r * 48;
            int sh = h0 + r + dh, sw = w + dw;
            short8 val = (short8){0,0,0,0,0,0,0,0};
            if ((unsigned)sh < 48u && (unsigned)sw < 48u)
                val = *(const short8*)(xb + (size_t)(sh * 48 + sw) * CC + cv * 8);
            *(short8*)(slab + pr * 128 + ((cv ^ (pr & 7)) * 8)) = val;
        }
        __syncthreads();
        #pragma unroll
        for (int kc = 0; kc < 4; ++kc) {
            short8 bfr = *(const short8*)(wb_ref + tap * 16384 + (o0 + fr) * 128 + kc * 32 + fg * 8);
            #pragma unroll
            for (int pt = 0; pt < 9; ++pt) {
                int prr = pt * 16 + fr;
                short8 pa = *(const short8*)(slab + prr * 128 + (((kc * 4 + fg) ^ (prr & 7)) * 8));
                acc[pt] = __builtin_amdgcn_mfma_f32_16x16x32_bf16(pa, bfr, acc[pt], 0, 0, 0);
            }
        }
    }
    int o = o0 + fr;
    float bias = rb[o];
    #pragma unroll
    for (int pt = 0; pt < 9; ++pt) {
        #pragma unroll
        for (int r = 0; r < 4; ++r) {
            int p = p0g + pt * 16 + fg * 4 + r;
            size_t off = ((size_t)b * NTOK + p) * CC + o;
            float v = acc[pt][r] + bias + rbuf[off];
            xt2[off] = f2bf(v);
        }
    }
}

// ---------------- Kernel 5: coverage conv (dil 2) as implicit MFMA GEMM ----
__global__ __launch_bounds__(256) void covgemm_kernel(
    const u16* __restrict__ xt2, const u16* __restrict__ wb_cov,
    const float* __restrict__ cb, float* __restrict__ out)
{
    __shared__ u16 slab[144 * 128];
    __shared__ float ldsout[4 * 16 * 145];   // per-wave [o][p] staging, padded
    int tid = threadIdx.x;
    int lane = tid & 63, wid = tid >> 6;
    int blk = blockIdx.x;
    int b  = blk & 7;
    int st = (blk >> 3) & 15;
    int oh = blk >> 7;
    int h0 = st * 3;
    int p0g = st * 144;
    int fr = lane & 15, fg = lane >> 4;
    int o0 = oh * 64 + wid * 16;
    const u16* xb = xt2 + (size_t)b * NTOK * CC;

    f32x4 acc[9];
    #pragma unroll
    for (int pt = 0; pt < 9; ++pt) acc[pt] = (f32x4){0.f, 0.f, 0.f, 0.f};

    for (int tap = 0; tap < 9; ++tap) {
        int dh = (tap / 3 - 1) * 2, dw = (tap % 3 - 1) * 2;
        __syncthreads();
        #pragma unroll
        for (int it = 0; it < 9; ++it) {
            int idx = it * 256 + tid;
            int pr = idx >> 4, cv = idx & 15;
            int r = pr >= 96 ? 2 : (pr >= 48 ? 1 : 0);
            int w = pr - r * 48;
            int sh = h0 + r + dh, sw = w + dw;
            short8 val = (short8){0,0,0,0,0,0,0,0};
            if ((unsigned)sh < 48u && (unsigned)sw < 48u)
                val = *(const short8*)(xb + (size_t)(sh * 48 + sw) * CC + cv * 8);
            *(short8*)(slab + pr * 128 + ((cv ^ (pr & 7)) * 8)) = val;
        }
        __syncthreads();
        #pragma unroll
        for (int kc = 0; kc < 4; ++kc) {
            short8 bfr = *(const short8*)(wb_cov + tap * 16384 + (o0 + fr) * 128 + kc * 32 + fg * 8);
            #pragma unroll
            for (int pt = 0; pt < 9; ++pt) {
                int prr = pt * 16 + fr;
                short8 pa = *(const short8*)(slab + prr * 128 + (((kc * 4 + fg) ^ (prr & 7)) * 8));
                acc[pt] = __builtin_amdgcn_mfma_f32_16x16x32_bf16(pa, bfr, acc[pt], 0, 0, 0);
            }
        }
    }
    // stage [16 o][144 p] per wave, then coalesced plane-order stores
    float bias = cb[o0 + fr];
    float* lo = ldsout + wid * (16 * 145);
    #pragma unroll
    for (int pt = 0; pt < 9; ++pt) {
        #pragma unroll
        for (int r = 0; r < 4; ++r) {
            int pl = pt * 16 + fg * 4 + r;
            lo[fr * 145 + pl] = acc[pt][r] + bias;
        }
    }
    __syncthreads();
    float* ob = out + ((size_t)b * CC + o0) * NTOK + p0g;
    #pragma unroll
    for (int j = 0; j < 36; ++j) {
        int idx = j * 64 + lane;         // 0..2303
        int o_r = idx / 144;
        int p_r = idx - o_r * 144;
        ob[(size_t)o_r * NTOK + p_r] = lo[o_r * 145 + p_r];
    }
}

extern "C" void kernel_launch(void* const* d_in, const int* in_sizes, int n_in,
                              void* d_out, int out_size, void* d_ws, size_t ws_size,
                              hipStream_t stream)
{
    const float* x    = (const float*)d_in[0];
    const float* prev = (const float*)d_in[1];
    const float* Wq   = (const float*)d_in[2];
    const float* bq   = (const float*)d_in[3];
    const float* Wk   = (const float*)d_in[4];
    const float* bk   = (const float*)d_in[5];
    const float* Wv   = (const float*)d_in[6];
    const float* bv   = (const float*)d_in[7];
    const float* rw   = (const float*)d_in[8];
    const float* rb   = (const float*)d_in[9];
    const float* gw   = (const float*)d_in[10];
    const float* gb   = (const float*)d_in[11];
    const float* cw   = (const float*)d_in[12];
    const float* cb   = (const float*)d_in[13];
    float* out = (float*)d_out;
    char* ws = (char*)d_ws;

    const size_t SZ  = (size_t)BB * NTOK * CC;   // 2359296 elements
    const size_t BSZ = SZ * 2;                   // bf16 bytes
    const size_t FSZ = SZ * 4;                   // fp32 bytes
    u16*   q_ws   = (u16*)(ws);
    u16*   k_ws   = (u16*)(ws + BSZ);
    u16*   v_ws   = (u16*)(ws + 2 * BSZ);
    float* xs_ws  = (float*)(ws + 3 * BSZ);
    float* imp_ws = (float*)(ws + 3 * BSZ + FSZ);
    u16*   xt_g   = (u16*)(ws + 3 * BSZ + FSZ + 73728);
    float* rbuf   = (float*)(ws + 4 * BSZ + FSZ + 73728);
    u16*   xt2    = (u16*)(ws + 4 * BSZ + 2 * FSZ + 73728);
    u16*   wb_ref = (u16*)(ws + 5 * BSZ + 2 * FSZ + 73728);
    u16*   wb_cov = (u16*)(ws + 5 * BSZ + 2 * FSZ + 73728 + 294912);
    // total ~43.1 MB

    qkv_kernel<<<dim3(288), dim3(256), 0, stream>>>(x, Wq, bq, Wk, bk, Wv, bv,
                                                    q_ws, k_ws, v_ws);
    attn_kernel<<<dim3(1152), dim3(512), 0, stream>>>(q_ws, k_ws, v_ws, xs_ws);
    gate_kernel<<<dim3(288), dim3(256), 0, stream>>>(xs_ws, gw, gb, imp_ws);
    wtrans_kernel<<<dim3(1152), dim3(256), 0, stream>>>(rw, cw, wb_ref, wb_cov);
    tpos_kernel<<<dim3(288), dim3(256), 0, stream>>>(xs_ws, prev, imp_ws, xt_g, rbuf);
    refgemm_kernel<<<dim3(256), dim3(256), 0, stream>>>(xt_g, wb_ref, rbuf, rb, xt2);
    covgemm_kernel<<<dim3(256), dim3(256), 0, stream>>>(xt2, wb_cov, cb, out);
}